// Round 7
// baseline (244.554 us; speedup 1.0000x reference)
//
#include <hip/hip_runtime.h>
#include <hip/hip_cooperative_groups.h>
#include <math.h>

namespace cg = cooperative_groups;

// TripletLoss round 7: single cooperative fused kernel (512 blocks @ 2/CU,
// safe occupancy margin) with host-side fallback to the 3-kernel pipeline.
// No memsets, no global atomics except the final 32 atomicAdds on out.
//
// Per column j: d2_ij = sq_j + 2*(u_i - acc_ij), u = sq/2 (tag in low 8 mantissa).
//   sum_all_j = N*sq_j + S_all     - 2*Sa_j
//   sum_p_j   = cnt*sq_j + S_class - 2*Ss_j
//   max_p d2  = sq_j + 2*max_same(u_i - acc)
//   min_n d2  = sq_j + 2*min_diff(u_i - acc)
// Self positive absorbed analytically in sum_p (bf16 noise/(cnt-1) ~1e-5 rel).

#define NROWS 8192
#define MARGIN_F 0.3f

// ws float-offsets
#define OFF_SQ   0          // float[8192]
#define OFF_UPK  8192       // float[8192]
#define OFF_XBF  16384      // bf16[1M] = 262144 float slots
#define OFF_PART 278528     // 4 * 8192 float4 = 131072 float slots (end 409600)

typedef short bf16x8 __attribute__((ext_vector_type(8)));
typedef float f32x16 __attribute__((ext_vector_type(16)));
union U4B { uint4 u; bf16x8 h; };

__device__ __forceinline__ unsigned short f2bf(float x) {
    unsigned u = __float_as_uint(x);
    return (unsigned short)((u + 0x7fffu + ((u >> 16) & 1u)) >> 16);
}

// ================= phase 0: prep (16 rows / block, 512 blocks) =================
__device__ __forceinline__ void phase_prep(int bx, const float* __restrict__ X,
                                           const int* __restrict__ tgt,
                                           float* __restrict__ sq,
                                           float* __restrict__ upk,
                                           unsigned short* __restrict__ Xbf,
                                           float* __restrict__ out) {
    int tid = threadIdx.x, w = tid >> 6, l = tid & 63;
    #pragma unroll
    for (int i = 0; i < 4; ++i) {
        int r = bx * 16 + w * 4 + i;
        float2 v = ((const float2*)X)[(size_t)r * 64 + l];
        ushort2 h2;
        h2.x = f2bf(v.x);
        h2.y = f2bf(v.y);
        ((ushort2*)Xbf)[(size_t)r * 64 + l] = h2;
        float s = v.x * v.x + v.y * v.y;
        for (int d = 32; d > 0; d >>= 1) s += __shfl_down(s, d, 64);
        if (l == 0) {
            sq[r] = s;
            upk[r] = __uint_as_float((__float_as_uint(0.5f * s) & 0xffffff00u)
                                     | (unsigned)tgt[r]);
        }
    }
    if (bx == 0 && tid == 0) out[0] = 0.0f;   // ordered before combine's atomicAdd
}

// ===== phase 1: MFMA Gram + column stats (4 slices x 128 strips, 512 blocks) =====
__device__ __forceinline__ void phase_dist(int bx,
                                           const unsigned short* __restrict__ Xbf,
                                           const int* __restrict__ tgt,
                                           const float* __restrict__ upk,
                                           float4* __restrict__ partial) {
    __shared__ uint4 As[128 * 16];
    __shared__ float ush[128];
    const int tid = threadIdx.x;
    const int w = tid >> 6, l = tid & 63, hl = l >> 5, l31 = l & 31;
    const int slice = bx & 3;   // XCD k (bx%8) hosts one slice value -> A L2-local
    const int jb = bx >> 2;     // 64-col strip, 0..127

    // stage this block's 64 B-columns via LDS (swizzled), build register frags
    {
        const uint4* src = (const uint4*)Xbf + (size_t)jb * 64 * 16;
        #pragma unroll
        for (int s = 0; s < 4; ++s) {
            int g = s * 256 + tid, row = g >> 4, c = g & 15;
            As[row * 16 + (c ^ (row & 15))] = src[g];
        }
    }
    __syncthreads();
    bf16x8 Bf[2][8];
    int tjt[2];
    #pragma unroll
    for (int ct = 0; ct < 2; ++ct) {
        int colb = ct * 32 + l31;
        tjt[ct] = tgt[jb * 64 + colb];
        #pragma unroll
        for (int kk = 0; kk < 8; ++kk) {
            U4B t; t.u = As[colb * 16 + ((kk * 2 + hl) ^ (colb & 15))];
            Bf[ct][kk] = t.h;
        }
    }

    float Sa[2] = {0.f, 0.f};
    float Ss[2] = {0.f, 0.f};
    float Mp[2] = {-INFINITY, -INFINITY};
    float Mn[2] = { INFINITY,  INFINITY};

    for (int t = 0; t < 16; ++t) {
        const int i0 = slice * 2048 + t * 128;
        __syncthreads();
        {
            const uint4* src = (const uint4*)Xbf + (size_t)i0 * 16;
            #pragma unroll
            for (int s = 0; s < 8; ++s) {
                int g = s * 256 + tid, row = g >> 4, c = g & 15;
                As[row * 16 + (c ^ (row & 15))] = src[g];
            }
            if (tid < 128) ush[tid] = upk[i0 + tid];
        }
        __syncthreads();

        float ur[16];
        int tags[16];
        #pragma unroll
        for (int r = 0; r < 16; ++r) {
            ur[r] = ush[w * 32 + (r & 3) + 8 * (r >> 2) + 4 * hl];
            tags[r] = __float_as_int(ur[r]) & 0xff;
        }

        f32x16 acc[2];
        acc[0] = (f32x16)0.0f;
        acc[1] = (f32x16)0.0f;
        const int arow = w * 32 + l31;
        #pragma unroll
        for (int kk = 0; kk < 8; ++kk) {
            U4B a; a.u = As[arow * 16 + ((kk * 2 + hl) ^ (arow & 15))];
            acc[0] = __builtin_amdgcn_mfma_f32_32x32x16_bf16(a.h, Bf[0][kk], acc[0], 0, 0, 0);
            acc[1] = __builtin_amdgcn_mfma_f32_32x32x16_bf16(a.h, Bf[1][kk], acc[1], 0, 0, 0);
        }

        #pragma unroll
        for (int ct = 0; ct < 2; ++ct) {
            const int tt = tjt[ct];
            #pragma unroll
            for (int r = 0; r < 16; ++r) {
                float a = acc[ct][r];
                float v = ur[r] - a;
                bool same = (tags[r] == tt);
                Sa[ct] += a;
                Ss[ct] += same ? a : 0.0f;
                Mp[ct] = fmaxf(Mp[ct], same ? v : -INFINITY);
                Mn[ct] = same ? Mn[ct] : fminf(Mn[ct], v);
            }
        }
    }

    // merge half-lanes, then 4 waves via LDS, write coalesced partial
    #pragma unroll
    for (int ct = 0; ct < 2; ++ct) {
        Sa[ct] += __shfl_xor(Sa[ct], 32, 64);
        Ss[ct] += __shfl_xor(Ss[ct], 32, 64);
        Mp[ct] = fmaxf(Mp[ct], __shfl_xor(Mp[ct], 32, 64));
        Mn[ct] = fminf(Mn[ct], __shfl_xor(Mn[ct], 32, 64));
    }
    __syncthreads();
    float4* sm = (float4*)As;     // [64 cols][4 waves]
    if (l < 32) {
        #pragma unroll
        for (int ct = 0; ct < 2; ++ct)
            sm[(ct * 32 + l31) * 4 + w] = make_float4(Sa[ct], Ss[ct], Mp[ct], Mn[ct]);
    }
    __syncthreads();
    if (tid < 64) {
        float4 a = sm[tid * 4 + 0], b = sm[tid * 4 + 1];
        float4 c2 = sm[tid * 4 + 2], d = sm[tid * 4 + 3];
        float4 o;
        o.x = a.x + b.x + c2.x + d.x;
        o.y = a.y + b.y + c2.y + d.y;
        o.z = fmaxf(fmaxf(a.z, b.z), fmaxf(c2.z, d.z));
        o.w = fminf(fminf(a.w, b.w), fminf(c2.w, d.w));
        partial[(size_t)slice * NROWS + jb * 64 + tid] = o;
    }
}

// ===== phase 2: class tables in LDS + per-row loss + atomicAdd (32 blocks) =====
__device__ __forceinline__ void phase_combine(int bx, const int* __restrict__ tgt,
                                              const float* __restrict__ sq,
                                              const float4* __restrict__ partial,
                                              float* __restrict__ out) {
    __shared__ float scl[256];
    __shared__ int cnt[256];
    __shared__ float red[4];
    __shared__ float hs[4];
    int tid = threadIdx.x, w = tid >> 6, l = tid & 63;
    scl[tid] = 0.0f;
    cnt[tid] = 0;
    __syncthreads();
    for (int it = 0; it < 32; ++it) {
        int r = it * 256 + tid;
        int c = tgt[r];
        atomicAdd(&scl[c], sq[r]);
        atomicAdd(&cnt[c], 1);
    }
    __syncthreads();
    float s = scl[tid];
    for (int d = 32; d > 0; d >>= 1) s += __shfl_down(s, d, 64);
    if (l == 0) red[w] = s;
    __syncthreads();
    float S_all = red[0] + red[1] + red[2] + red[3];

    int j = bx * 256 + tid;
    float Sa = 0.f, Ss = 0.f, Mp = -INFINITY, Mn = INFINITY;
    #pragma unroll
    for (int s2 = 0; s2 < 4; ++s2) {
        float4 p = partial[(size_t)s2 * NROWS + j];
        Sa += p.x; Ss += p.y;
        Mp = fmaxf(Mp, p.z); Mn = fminf(Mn, p.w);
    }
    float sqj = sq[j];
    int c = tgt[j];
    float cm = (float)cnt[c];
    float sumall = (float)NROWS * sqj + S_all - 2.0f * Sa;
    float sump = cm * sqj + scl[c] - 2.0f * Ss;
    float sumn = sumall - sump;
    float sigp = sump / (cm - 1.0f);
    float sign_ = sumn / ((float)NROWS - cm);
    float ap = (sqj + 2.0f * Mp) / sigp + 0.5f * __logf(sigp);
    float an = (sqj + 2.0f * Mn) / sign_ + 0.5f * __logf(sign_);
    float h = fmaxf(ap - an + MARGIN_F, 0.0f);
    for (int d = 32; d > 0; d >>= 1) h += __shfl_down(h, d, 64);
    if (l == 0) hs[w] = h;
    __syncthreads();
    if (tid == 0)
        atomicAdd(out, (hs[0] + hs[1] + hs[2] + hs[3]) * (1.0f / NROWS));
}

// ================= fused cooperative kernel =================
__global__ __launch_bounds__(256, 2) void fused_kernel(
        const float* __restrict__ X, const int* __restrict__ tgt,
        float* __restrict__ f, float* __restrict__ out) {
    float* sq  = f + OFF_SQ;
    float* upk = f + OFF_UPK;
    unsigned short* Xbf = (unsigned short*)(f + OFF_XBF);
    float4* partial = (float4*)(f + OFF_PART);

    phase_prep(blockIdx.x, X, tgt, sq, upk, Xbf, out);
    cg::this_grid().sync();
    phase_dist(blockIdx.x, Xbf, tgt, upk, partial);
    cg::this_grid().sync();
    if (blockIdx.x < 32) phase_combine(blockIdx.x, tgt, sq, partial, out);
}

// ================= fallback standalone kernels =================
__global__ __launch_bounds__(256, 2) void prep_k(const float* __restrict__ X,
                                                 const int* __restrict__ tgt,
                                                 float* __restrict__ sq,
                                                 float* __restrict__ upk,
                                                 unsigned short* __restrict__ Xbf,
                                                 float* __restrict__ out) {
    phase_prep(blockIdx.x, X, tgt, sq, upk, Xbf, out);
}

__global__ __launch_bounds__(256, 2) void dist_k(const unsigned short* __restrict__ Xbf,
                                                 const int* __restrict__ tgt,
                                                 const float* __restrict__ upk,
                                                 float4* __restrict__ partial) {
    phase_dist(blockIdx.x, Xbf, tgt, upk, partial);
}

__global__ __launch_bounds__(256) void combine_k(const int* __restrict__ tgt,
                                                 const float* __restrict__ sq,
                                                 const float4* __restrict__ partial,
                                                 float* __restrict__ out) {
    phase_combine(blockIdx.x, tgt, sq, partial, out);
}

extern "C" void kernel_launch(void* const* d_in, const int* in_sizes, int n_in,
                              void* d_out, int out_size, void* d_ws, size_t ws_size,
                              hipStream_t stream) {
    const float* X = (const float*)d_in[0];
    const int* tgt = (const int*)d_in[1];
    float* out = (float*)d_out;
    float* f = (float*)d_ws;

    void* args[] = { (void*)&X, (void*)&tgt, (void*)&f, (void*)&out };
    hipError_t e = hipLaunchCooperativeKernel((const void*)fused_kernel,
                                              dim3(512), dim3(256), args, 0, stream);
    if (e != hipSuccess) {
        (void)hipGetLastError();   // clear sticky error, take the classic path
        float* sq  = f + OFF_SQ;
        float* upk = f + OFF_UPK;
        unsigned short* Xbf = (unsigned short*)(f + OFF_XBF);
        float4* partial = (float4*)(f + OFF_PART);
        prep_k<<<512, 256, 0, stream>>>(X, tgt, sq, upk, Xbf, out);
        dist_k<<<512, 256, 0, stream>>>(Xbf, tgt, upk, partial);
        combine_k<<<32, 256, 0, stream>>>(tgt, sq, partial, out);
    }
}

// Round 8
// 120.430 us; speedup vs baseline: 2.0307x; 2.0307x over previous
//
#include <hip/hip_runtime.h>
#include <math.h>

// TripletLoss round 8: r5 split pipeline (coop abandoned — r7 showed 179us
// intrinsic vs ~55us split), occupancy fix: __launch_bounds__(256,4) on dist
// (needs ~112 regs incl AGPR <= 128 cap), 3 nodes, no memsets, no global
// atomics except 32 adds on out.
//
// Per column j: d2_ij = sq_j + 2*(u_i - acc_ij), u = sq/2 (tag in low 8 mantissa).
//   sum_all_j = N*sq_j + S_all     - 2*Sa_j
//   sum_p_j   = cnt*sq_j + S_class - 2*Ss_j
//   max_p d2  = sq_j + 2*max_same(u_i - acc)
//   min_n d2  = sq_j + 2*min_diff(u_i - acc)
// Self positive absorbed analytically in sum_p (bf16 noise/(cnt-1) ~1e-5 rel).

#define NROWS 8192
#define MARGIN_F 0.3f

// ws float-offsets
#define OFF_SQ   0          // float[8192]
#define OFF_UPK  8192       // float[8192]
#define OFF_XBF  16384      // bf16[1M] = 524288 float slots
#define OFF_PART 540672     // ns * 8192 float4

typedef short bf16x8 __attribute__((ext_vector_type(8)));
typedef float f32x16 __attribute__((ext_vector_type(16)));
union U4B { uint4 u; bf16x8 h; };

__device__ __forceinline__ unsigned short f2bf(float x) {
    unsigned u = __float_as_uint(x);
    return (unsigned short)((u + 0x7fffu + ((u >> 16) & 1u)) >> 16);
}

// ---- K1: bf16 convert + sq + tagged u (512 blocks, 16 rows each) ----
__global__ __launch_bounds__(256) void prep_kernel(const float* __restrict__ X,
                                                   const int* __restrict__ tgt,
                                                   float* __restrict__ sq,
                                                   float* __restrict__ upk,
                                                   unsigned short* __restrict__ Xbf,
                                                   float* __restrict__ out) {
    int tid = threadIdx.x, w = tid >> 6, l = tid & 63;
    #pragma unroll
    for (int i = 0; i < 4; ++i) {
        int r = blockIdx.x * 16 + w * 4 + i;
        float2 v = ((const float2*)X)[(size_t)r * 64 + l];
        ushort2 h2;
        h2.x = f2bf(v.x);
        h2.y = f2bf(v.y);
        ((ushort2*)Xbf)[(size_t)r * 64 + l] = h2;
        float s = v.x * v.x + v.y * v.y;
        for (int d = 32; d > 0; d >>= 1) s += __shfl_down(s, d, 64);
        if (l == 0) {
            sq[r] = s;
            upk[r] = __uint_as_float((__float_as_uint(0.5f * s) & 0xffffff00u)
                                     | (unsigned)tgt[r]);
        }
    }
    if (blockIdx.x == 0 && tid == 0) out[0] = 0.0f;  // stream-ordered before combine
}

// ---- K2: MFMA Gram + fused column stats (128*ns blocks, 4 blocks/CU) ----
__global__ __launch_bounds__(256, 4) void dist_kernel(
        const unsigned short* __restrict__ Xbf, const int* __restrict__ tgt,
        const float* __restrict__ upk, float4* __restrict__ partial,
        int ns_mask, int jb_shift, int tiles) {
    __shared__ uint4 As[128 * 16];
    __shared__ float ush[128];
    const int tid = threadIdx.x;
    const int w = tid >> 6, l = tid & 63, hl = l >> 5, l31 = l & 31;
    const int bx = blockIdx.x;
    const int slice = bx & ns_mask;   // bx%8 = XCD: each XCD sees ns/8 slices -> A L2-local
    const int jb = bx >> jb_shift;    // 64-col strip

    // stage this block's 64 B-columns (16 KB) via LDS (swizzled), build frags
    {
        const uint4* src = (const uint4*)Xbf + (size_t)jb * 64 * 16;
        #pragma unroll
        for (int s = 0; s < 4; ++s) {
            int g = s * 256 + tid, row = g >> 4, c = g & 15;
            As[row * 16 + (c ^ (row & 15))] = src[g];
        }
    }
    __syncthreads();
    bf16x8 Bf[2][8];
    int tjt[2];
    #pragma unroll
    for (int ct = 0; ct < 2; ++ct) {
        int colb = ct * 32 + l31;
        tjt[ct] = tgt[jb * 64 + colb];
        #pragma unroll
        for (int kk = 0; kk < 8; ++kk) {
            U4B t; t.u = As[colb * 16 + ((kk * 2 + hl) ^ (colb & 15))];
            Bf[ct][kk] = t.h;
        }
    }

    float Sa[2] = {0.f, 0.f};
    float Ss[2] = {0.f, 0.f};
    float Mp[2] = {-INFINITY, -INFINITY};
    float Mn[2] = { INFINITY,  INFINITY};

    for (int t = 0; t < tiles; ++t) {
        const int i0 = (slice * tiles + t) * 128;
        __syncthreads();
        {
            const uint4* src = (const uint4*)Xbf + (size_t)i0 * 16;
            #pragma unroll
            for (int s = 0; s < 8; ++s) {
                int g = s * 256 + tid, row = g >> 4, c = g & 15;
                As[row * 16 + (c ^ (row & 15))] = src[g];
            }
            if (tid < 128) ush[tid] = upk[i0 + tid];
        }
        __syncthreads();

        float ur[16];
        int tags[16];
        #pragma unroll
        for (int r = 0; r < 16; ++r) {
            ur[r] = ush[w * 32 + (r & 3) + 8 * (r >> 2) + 4 * hl];
            tags[r] = __float_as_int(ur[r]) & 0xff;
        }

        f32x16 acc[2];
        acc[0] = (f32x16)0.0f;
        acc[1] = (f32x16)0.0f;
        const int arow = w * 32 + l31;
        #pragma unroll
        for (int kk = 0; kk < 8; ++kk) {
            U4B a; a.u = As[arow * 16 + ((kk * 2 + hl) ^ (arow & 15))];
            acc[0] = __builtin_amdgcn_mfma_f32_32x32x16_bf16(a.h, Bf[0][kk], acc[0], 0, 0, 0);
            acc[1] = __builtin_amdgcn_mfma_f32_32x32x16_bf16(a.h, Bf[1][kk], acc[1], 0, 0, 0);
        }

        #pragma unroll
        for (int ct = 0; ct < 2; ++ct) {
            const int tt = tjt[ct];
            #pragma unroll
            for (int r = 0; r < 16; ++r) {
                float a = acc[ct][r];
                float v = ur[r] - a;
                bool same = (tags[r] == tt);
                Sa[ct] += a;
                Ss[ct] += same ? a : 0.0f;
                Mp[ct] = fmaxf(Mp[ct], same ? v : -INFINITY);
                Mn[ct] = same ? Mn[ct] : fminf(Mn[ct], v);
            }
        }
    }

    // merge half-lanes, then 4 waves via LDS, write coalesced partial
    #pragma unroll
    for (int ct = 0; ct < 2; ++ct) {
        Sa[ct] += __shfl_xor(Sa[ct], 32, 64);
        Ss[ct] += __shfl_xor(Ss[ct], 32, 64);
        Mp[ct] = fmaxf(Mp[ct], __shfl_xor(Mp[ct], 32, 64));
        Mn[ct] = fminf(Mn[ct], __shfl_xor(Mn[ct], 32, 64));
    }
    __syncthreads();
    float4* sm = (float4*)As;     // [64 cols][4 waves]
    if (l < 32) {
        #pragma unroll
        for (int ct = 0; ct < 2; ++ct)
            sm[(ct * 32 + l31) * 4 + w] = make_float4(Sa[ct], Ss[ct], Mp[ct], Mn[ct]);
    }
    __syncthreads();
    if (tid < 64) {
        float4 a = sm[tid * 4 + 0], b = sm[tid * 4 + 1];
        float4 c2 = sm[tid * 4 + 2], d = sm[tid * 4 + 3];
        float4 o;
        o.x = a.x + b.x + c2.x + d.x;
        o.y = a.y + b.y + c2.y + d.y;
        o.z = fmaxf(fmaxf(a.z, b.z), fmaxf(c2.z, d.z));
        o.w = fminf(fminf(a.w, b.w), fminf(c2.w, d.w));
        partial[(size_t)slice * NROWS + jb * 64 + tid] = o;
    }
}

// ---- K3: class tables in LDS + per-row loss + atomicAdd out (32 blocks) ----
__global__ __launch_bounds__(256) void combine_kernel(
        const int* __restrict__ tgt, const float* __restrict__ sq,
        const float4* __restrict__ partial, float* __restrict__ out, int ns) {
    __shared__ float scl[256];
    __shared__ int cnt[256];
    __shared__ float red[4];
    __shared__ float hs[4];
    int tid = threadIdx.x, w = tid >> 6, l = tid & 63;
    scl[tid] = 0.0f;
    cnt[tid] = 0;
    __syncthreads();
    for (int it = 0; it < 32; ++it) {
        int r = it * 256 + tid;
        int c = tgt[r];
        atomicAdd(&scl[c], sq[r]);
        atomicAdd(&cnt[c], 1);
    }
    __syncthreads();
    float s = scl[tid];
    for (int d = 32; d > 0; d >>= 1) s += __shfl_down(s, d, 64);
    if (l == 0) red[w] = s;
    __syncthreads();
    float S_all = red[0] + red[1] + red[2] + red[3];

    int j = blockIdx.x * 256 + tid;
    float Sa = 0.f, Ss = 0.f, Mp = -INFINITY, Mn = INFINITY;
    for (int s2 = 0; s2 < ns; ++s2) {
        float4 p = partial[(size_t)s2 * NROWS + j];
        Sa += p.x; Ss += p.y;
        Mp = fmaxf(Mp, p.z); Mn = fminf(Mn, p.w);
    }
    float sqj = sq[j];
    int c = tgt[j];
    float cm = (float)cnt[c];
    float sumall = (float)NROWS * sqj + S_all - 2.0f * Sa;
    float sump = cm * sqj + scl[c] - 2.0f * Ss;
    float sumn = sumall - sump;
    float sigp = sump / (cm - 1.0f);
    float sign_ = sumn / ((float)NROWS - cm);
    float ap = (sqj + 2.0f * Mp) / sigp + 0.5f * __logf(sigp);
    float an = (sqj + 2.0f * Mn) / sign_ + 0.5f * __logf(sign_);
    float h = fmaxf(ap - an + MARGIN_F, 0.0f);
    for (int d = 32; d > 0; d >>= 1) h += __shfl_down(h, d, 64);
    if (l == 0) hs[w] = h;
    __syncthreads();
    if (tid == 0)
        atomicAdd(out, (hs[0] + hs[1] + hs[2] + hs[3]) * (1.0f / NROWS));
}

extern "C" void kernel_launch(void* const* d_in, const int* in_sizes, int n_in,
                              void* d_out, int out_size, void* d_ws, size_t ws_size,
                              hipStream_t stream) {
    const float* X = (const float*)d_in[0];
    const int* tgt = (const int*)d_in[1];
    float* out = (float*)d_out;
    float* f = (float*)d_ws;

    float* sq  = f + OFF_SQ;
    float* upk = f + OFF_UPK;
    unsigned short* Xbf = (unsigned short*)(f + OFF_XBF);
    float4* partial = (float4*)(f + OFF_PART);

    int ns = 16;   // j-slices: 128*ns blocks, 64/ns tiles each
    while (ns > 2 && ws_size < ((size_t)OFF_PART + (size_t)ns * NROWS * 4) * sizeof(float))
        ns >>= 1;
    int shift = (ns == 16) ? 4 : (ns == 8) ? 3 : 2;
    int tiles = 64 / ns;

    prep_kernel<<<512, 256, 0, stream>>>(X, tgt, sq, upk, Xbf, out);
    dist_kernel<<<128 * ns, 256, 0, stream>>>(Xbf, tgt, upk, partial,
                                              ns - 1, shift, tiles);
    combine_kernel<<<32, 256, 0, stream>>>(tgt, sq, partial, out, ns);
}